// Round 8
// baseline (127.353 us; speedup 1.0000x reference)
//
#include <hip/hip_runtime.h>

#define Bc 8
#define Tc 8
#define Cc 32
#define Hc 16
#define Wc 28
#define NHc 4
#define DKc 8
#define HWc (Hc*Wc)                  // 448
#define INV_SCALE 0.35355339059327373f
#define LN_EPSc 1e-5f

typedef _Float16 half8 __attribute__((ext_vector_type(8)));

// Global layouts:
//   Q     : [bh][t][j4][hw]    float4   (pre-scaled by INV_SCALE)
//   K,V   : [bh][s][hw][dk]    float    (contiguous slice for LDS staging)
//   Tpart : [bh][s][t][hw]     half8    (fp16 partials)
//   LM    : [bh][s][t][hw]     float2   (l = sum exp, m = max score)

// ---------------------------------------------------------------------------
// Kernel 1: QKV projection + fused LayerNorm of q.
// grid = 256, 448 threads.  blk = head*64 + bt (XCD co-location of the
// 4 blocks sharing one bt slice of first/x).
// ---------------------------------------------------------------------------
__global__ __launch_bounds__(448) void qkv_ln_kernel(
    const float* __restrict__ first, const float* __restrict__ x,
    const float* __restrict__ Wq, const float* __restrict__ Wk,
    const float* __restrict__ Wv,
    const float* __restrict__ gamma, const float* __restrict__ beta,
    float4* __restrict__ Q, float* __restrict__ K, float* __restrict__ V)
{
    int blk  = blockIdx.x;           // head*64 + bt
    int head = blk >> 6;
    int bt   = blk & 63;             // b*T + t
    int t    = bt % Tc;
    int b    = bt / Tc;
    int tid  = threadIdx.x;          // h*W + w

    const float* fp = first + (size_t)bt * Cc * HWc + tid;
    const float* xp = x     + (size_t)bt * Cc * HWc + tid;
    float fv[Cc], xv[Cc];
#pragma unroll
    for (int c = 0; c < Cc; ++c) { fv[c] = fp[c*HWc]; xv[c] = xp[c*HWc]; }

    float qv[DKc], kv[DKc], vv[DKc];
#pragma unroll
    for (int dk = 0; dk < DKc; ++dk) {
        int o = head*DKc + dk;       // lane-uniform -> scalar loads of weights
        float aq = 0.f, ak = 0.f, av = 0.f;
#pragma unroll
        for (int c = 0; c < Cc; ++c) {
            aq = fmaf(Wq[o*Cc+c], fv[c], aq);
            ak = fmaf(Wk[o*Cc+c], xv[c], ak);
            av = fmaf(Wv[o*Cc+c], xv[c], av);
        }
        qv[dk] = aq; kv[dk] = ak; vv[dk] = av;
    }

    int bh = b*NHc + head;
    float* kp = K + (((size_t)bh*Tc + t)*HWc + tid)*DKc;
    float* vp = V + (((size_t)bh*Tc + t)*HWc + tid)*DKc;
    *(float4*)(kp)   = make_float4(kv[0],kv[1],kv[2],kv[3]);
    *(float4*)(kp+4) = make_float4(kv[4],kv[5],kv[6],kv[7]);
    *(float4*)(vp)   = make_float4(vv[0],vv[1],vv[2],vv[3]);
    *(float4*)(vp+4) = make_float4(vv[4],vv[5],vv[6],vv[7]);

    // LayerNorm over (DK,H,W) = 3584 values for this (b,t,head)
    float s1 = 0.f, s2 = 0.f;
#pragma unroll
    for (int dk = 0; dk < DKc; ++dk) { s1 += qv[dk]; s2 += qv[dk]*qv[dk]; }
#pragma unroll
    for (int off = 32; off >= 1; off >>= 1) {
        s1 += __shfl_down(s1, off, 64);
        s2 += __shfl_down(s2, off, 64);
    }
    __shared__ float r1[8], r2[8];
    int wid = tid >> 6, lane = tid & 63;
    if (lane == 0) { r1[wid] = s1; r2[wid] = s2; }
    __syncthreads();
    float S1 = 0.f, S2 = 0.f;
#pragma unroll
    for (int wv2 = 0; wv2 < 7; ++wv2) { S1 += r1[wv2]; S2 += r2[wv2]; }
    const float invN = 1.f / (float)(DKc * HWc);
    float mu   = S1 * invN;
    float var  = S2 * invN - mu*mu;
    float rstd = rsqrtf(var + LN_EPSc);

    float qn[DKc];
#pragma unroll
    for (int dk = 0; dk < DKc; ++dk) {
        float gg = gamma[dk*HWc + tid];
        float bb = beta [dk*HWc + tid];
        qn[dk] = ((qv[dk] - mu) * rstd * gg + bb) * INV_SCALE;  // pre-scale
    }
    Q[(((size_t)bh*Tc + t)*2 + 0)*HWc + tid] = make_float4(qn[0],qn[1],qn[2],qn[3]);
    Q[(((size_t)bh*Tc + t)*2 + 1)*HWc + tid] = make_float4(qn[4],qn[5],qn[6],qn[7]);
}

// ---------------------------------------------------------------------------
// Kernel 2: attention.  t_batch = 4, grid = 512 single-item blocks.
// Stride-256 complementary-head pairing: XCD = blk%8, CU slot = (blk/8)%32,
// so blk and blk+256 are co-resident on one CU.  blk<256 -> heads {0,1},
// blk>=256 -> heads {3,2}: each CU holds one heavy + one light head
// (work h0+h3 = 50.6 vs h1+h2 = 42.9 units, max/mean 1.08).
// 14 waves/CU at t4's LDS-read rate.
// ---------------------------------------------------------------------------
__global__ __launch_bounds__(448, 4) void attn_kernel(
    const float4* __restrict__ Q, const float* __restrict__ K,
    const float* __restrict__ V,
    half8* __restrict__ Tpart, float2* __restrict__ LMpart)
{
    int blk = blockIdx.x;
    int p   = blk >> 8;              // pairing half
    int i   = blk & 255;
    int b   = i >> 5;
    int ha  = (i >> 4) & 1;
    int s   = (i >> 1) & 7;
    int th  = i & 1;

    int head = p ? (3 - ha) : ha;
    int dil  = 2*head + 1;           // {1,3,5,7}
    int bh   = b*NHc + head;
    int t0   = th*4;

    int tid = threadIdx.x;           // h*W + w
    int w = tid % Wc;
    int h = tid / Wc;

    __shared__ float4 sK0[HWc], sK1[HWc], sV0[HWc], sV1[HWc];  // 28672 B

    const float* kp = K + ((size_t)bh*Tc + s)*HWc*DKc;
    const float* vp = V + ((size_t)bh*Tc + s)*HWc*DKc;
    sK0[tid] = *(const float4*)(kp + tid*DKc);
    sK1[tid] = *(const float4*)(kp + tid*DKc + 4);
    sV0[tid] = *(const float4*)(vp + tid*DKc);
    sV1[tid] = *(const float4*)(vp + tid*DKc + 4);

    float4 q0[4], q1[4];
    const float4* qb = Q + (size_t)bh*Tc*2*HWc + tid;
#pragma unroll
    for (int j = 0; j < 4; ++j) {
        q0[j] = qb[((t0+j)*2+0)*HWc];
        q1[j] = qb[((t0+j)*2+1)*HWc];
    }

    float4 a0[4], a1[4];
    float l[4], m[4];
#pragma unroll
    for (int j = 0; j < 4; ++j) {
        a0[j] = make_float4(0.f,0.f,0.f,0.f);
        a1[j] = make_float4(0.f,0.f,0.f,0.f);
        l[j] = 0.f; m[j] = -1e30f;
    }

    __syncthreads();

    for (int dy = -3; dy <= 3; ++dy) {
        int hy = h + dy*dil;
        if ((unsigned)hy >= (unsigned)Hc) continue;   // exec-mask row skip
        int rowbase = hy*Wc;
#pragma unroll
        for (int dx = -3; dx <= 3; ++dx) {
            int wx = w + dx*dil;
            int wcl = min(max(wx, 0), Wc-1);
            bool cv = (unsigned)wx < (unsigned)Wc;
            float bias = cv ? 0.f : -1e30f;
            float mask = cv ? 1.f : 0.f;
            int idx = rowbase + wcl;
            float4 k0 = sK0[idx], k1 = sK1[idx];
            float4 v0 = sV0[idx], v1 = sV1[idx];
#pragma unroll
            for (int j = 0; j < 4; ++j) {
                float sc = q0[j].x*k0.x + q0[j].y*k0.y + q0[j].z*k0.z + q0[j].w*k0.w
                         + q1[j].x*k1.x + q1[j].y*k1.y + q1[j].z*k1.z + q1[j].w*k1.w;
                float msc = sc + bias;
                m[j] = fmaxf(m[j], msc);
                l[j] += __expf(msc);
                float z = sc * mask;
                a0[j].x = fmaf(z, v0.x, a0[j].x);
                a0[j].y = fmaf(z, v0.y, a0[j].y);
                a0[j].z = fmaf(z, v0.z, a0[j].z);
                a0[j].w = fmaf(z, v0.w, a0[j].w);
                a1[j].x = fmaf(z, v1.x, a1[j].x);
                a1[j].y = fmaf(z, v1.y, a1[j].y);
                a1[j].z = fmaf(z, v1.z, a1[j].z);
                a1[j].w = fmaf(z, v1.w, a1[j].w);
            }
        }
    }

    half8*  tp  = Tpart  + (size_t)(bh*Tc + s)*Tc*HWc + tid;
    float2* lmp = LMpart + (size_t)(bh*Tc + s)*Tc*HWc + tid;
#pragma unroll
    for (int j = 0; j < 4; ++j) {
        half8 hv;
        hv[0] = (_Float16)a0[j].x; hv[1] = (_Float16)a0[j].y;
        hv[2] = (_Float16)a0[j].z; hv[3] = (_Float16)a0[j].w;
        hv[4] = (_Float16)a1[j].x; hv[5] = (_Float16)a1[j].y;
        hv[6] = (_Float16)a1[j].z; hv[7] = (_Float16)a1[j].w;
        tp [(t0+j)*HWc] = hv;
        lmp[(t0+j)*HWc] = make_float2(l[j], m[j]);
    }
}

// ---------------------------------------------------------------------------
// Kernel 3: fused combine + output projection.
// grid = 256 blocks (blk = og*64 + bt; the 4 og blocks sharing one bt are 64
// apart -> same XCD, so the 4x replicated Tpart reads are L2-served).
// Each block reduces all 4 heads' s-partials (needed for all 32 channels),
// then projects its 8 output channels.
// ---------------------------------------------------------------------------
__global__ __launch_bounds__(448) void outproj_kernel(
    const half8* __restrict__ Tpart, const float2* __restrict__ LMpart,
    const float* __restrict__ Wo, float* __restrict__ out)
{
    int blk = blockIdx.x;            // og*64 + bt
    int og  = blk >> 6;
    int bt  = blk & 63;
    int b   = bt >> 3, t = bt & 7;
    int tid = threadIdx.x;           // h*W + w

    float mv[Cc];
    float MS = 0.f;
#pragma unroll
    for (int head = 0; head < NHc; ++head) {
        int bh = b*NHc + head;
        float acc[DKc];
#pragma unroll
        for (int j = 0; j < DKc; ++j) acc[j] = 0.f;
        float lsum = 0.f, mmax = -1e30f;
#pragma unroll
        for (int s = 0; s < Tc; ++s) {
            half8 u = Tpart[(size_t)((bh*Tc + s)*Tc + t)*HWc + tid];
#pragma unroll
            for (int j = 0; j < DKc; ++j) acc[j] += (float)u[j];
            float2 lm = LMpart[(size_t)((bh*Tc + s)*Tc + t)*HWc + tid];
            lsum += lm.x; mmax = fmaxf(mmax, lm.y);
        }
#pragma unroll
        for (int j = 0; j < DKc; ++j) mv[head*DKc + j] = acc[j];
        MS = fmaxf(MS, __expf(mmax) / lsum);
    }
#pragma unroll
    for (int i = 0; i < 8; ++i) {
        int o = og*8 + i;
        float a = 0.f;
#pragma unroll
        for (int c = 0; c < Cc; ++c) a = fmaf(Wo[o*Cc+c], mv[c], a);
        out[((size_t)bt*Cc + o)*HWc + tid] = a * MS;
    }
}

// ---------------------------------------------------------------------------
extern "C" void kernel_launch(void* const* d_in, const int* in_sizes, int n_in,
                              void* d_out, int out_size, void* d_ws, size_t ws_size,
                              hipStream_t stream) {
    const float* first = (const float*)d_in[0];
    const float* x     = (const float*)d_in[1];
    const float* Wq    = (const float*)d_in[2];
    const float* Wk    = (const float*)d_in[3];
    const float* Wv    = (const float*)d_in[4];
    const float* Wo    = (const float*)d_in[5];
    const float* g     = (const float*)d_in[6];
    const float* bta   = (const float*)d_in[7];
    float* out = (float*)d_out;

    float* ws = (float*)d_ws;
    const size_t N5 = (size_t)Bc*NHc*Tc*HWc*DKc;    // 917504 floats
    float4* Q   = (float4*)ws;                       // N5 floats
    float*  K   = ws +   N5;                         // N5
    float*  V   = ws + 2*N5;                         // N5
    half8*  Tp  = (half8*)(ws + 3*N5);               // 4*N5 floats
    float2* LMp = (float2*)(ws + 7*N5);              // 2*N5 floats
    // total: 9*N5 floats ~= 33 MB

    qkv_ln_kernel <<<Bc*Tc*NHc, 448, 0, stream>>>(first, x, Wq, Wk, Wv, g, bta, Q, K, V);
    attn_kernel   <<<512,       448, 0, stream>>>(Q, K, V, Tp, LMp);
    outproj_kernel<<<256,       448, 0, stream>>>(Tp, LMp, Wo, out);
}

// Round 10
// 113.789 us; speedup vs baseline: 1.1192x; 1.1192x over previous
//
#include <hip/hip_runtime.h>

#define Bc 8
#define Tc 8
#define Cc 32
#define Hc 16
#define Wc 28
#define NHc 4
#define DKc 8
#define HWc (Hc*Wc)                  // 448
#define INV_SCALE 0.35355339059327373f
#define LN_EPSc 1e-5f

typedef _Float16 half8  __attribute__((ext_vector_type(8)));
typedef _Float16 half2v __attribute__((ext_vector_type(2)));

union H8 { half8 v; half2v h2[4]; };

// Global layouts:
//   Qh    : [bh][t][hw]        half8    (LN'd, pre-scaled by INV_SCALE, fp16)
//   Kh    : [bh][s][hw]        half8    (fp16)
//   V     : [bh][s][hw][dk]    float
//   Tpart : [bh][s][t][hw]     half8    (fp16 partials)  = 4*N5 floats!
//   LM    : [bh][s][t][hw]     float2   (l = sum exp, m = max score)

// ---------------------------------------------------------------------------
// Kernel 1: QKV projection + fused LayerNorm of q.
// grid = 256, 448 threads.  blk = head*64 + bt (XCD co-location of the
// 4 blocks sharing one bt slice of first/x).
// ---------------------------------------------------------------------------
__global__ __launch_bounds__(448) void qkv_ln_kernel(
    const float* __restrict__ first, const float* __restrict__ x,
    const float* __restrict__ Wq, const float* __restrict__ Wk,
    const float* __restrict__ Wv,
    const float* __restrict__ gamma, const float* __restrict__ beta,
    half8* __restrict__ Qh, half8* __restrict__ Kh, float* __restrict__ V)
{
    int blk  = blockIdx.x;           // head*64 + bt
    int head = blk >> 6;
    int bt   = blk & 63;             // b*T + t
    int t    = bt % Tc;
    int b    = bt / Tc;
    int tid  = threadIdx.x;          // h*W + w

    const float* fp = first + (size_t)bt * Cc * HWc + tid;
    const float* xp = x     + (size_t)bt * Cc * HWc + tid;
    float fv[Cc], xv[Cc];
#pragma unroll
    for (int c = 0; c < Cc; ++c) { fv[c] = fp[c*HWc]; xv[c] = xp[c*HWc]; }

    float qv[DKc], kv[DKc], vv[DKc];
#pragma unroll
    for (int dk = 0; dk < DKc; ++dk) {
        int o = head*DKc + dk;       // lane-uniform -> scalar loads of weights
        float aq = 0.f, ak = 0.f, av = 0.f;
#pragma unroll
        for (int c = 0; c < Cc; ++c) {
            aq = fmaf(Wq[o*Cc+c], fv[c], aq);
            ak = fmaf(Wk[o*Cc+c], xv[c], ak);
            av = fmaf(Wv[o*Cc+c], xv[c], av);
        }
        qv[dk] = aq; kv[dk] = ak; vv[dk] = av;
    }

    int bh = b*NHc + head;
    half8 kh;
#pragma unroll
    for (int dk = 0; dk < DKc; ++dk) kh[dk] = (_Float16)kv[dk];
    Kh[((size_t)bh*Tc + t)*HWc + tid] = kh;

    float* vp = V + (((size_t)bh*Tc + t)*HWc + tid)*DKc;
    *(float4*)(vp)   = make_float4(vv[0],vv[1],vv[2],vv[3]);
    *(float4*)(vp+4) = make_float4(vv[4],vv[5],vv[6],vv[7]);

    // LayerNorm over (DK,H,W) = 3584 values for this (b,t,head)
    float s1 = 0.f, s2 = 0.f;
#pragma unroll
    for (int dk = 0; dk < DKc; ++dk) { s1 += qv[dk]; s2 += qv[dk]*qv[dk]; }
#pragma unroll
    for (int off = 32; off >= 1; off >>= 1) {
        s1 += __shfl_down(s1, off, 64);
        s2 += __shfl_down(s2, off, 64);
    }
    __shared__ float r1[8], r2[8];
    int wid = tid >> 6, lane = tid & 63;
    if (lane == 0) { r1[wid] = s1; r2[wid] = s2; }
    __syncthreads();
    float S1 = 0.f, S2 = 0.f;
#pragma unroll
    for (int wv2 = 0; wv2 < 7; ++wv2) { S1 += r1[wv2]; S2 += r2[wv2]; }
    const float invN = 1.f / (float)(DKc * HWc);
    float mu   = S1 * invN;
    float var  = S2 * invN - mu*mu;
    float rstd = rsqrtf(var + LN_EPSc);

    half8 qh;
#pragma unroll
    for (int dk = 0; dk < DKc; ++dk) {
        float gg = gamma[dk*HWc + tid];
        float bb = beta [dk*HWc + tid];
        qh[dk] = (_Float16)(((qv[dk] - mu) * rstd * gg + bb) * INV_SCALE);
    }
    Qh[((size_t)bh*Tc + t)*HWc + tid] = qh;
}

// ---------------------------------------------------------------------------
// Kernel 2: attention.  t_batch = 4, grid = 512 single-item blocks.
// Stride-256 complementary-head pairing (R8): blk and blk+256 co-resident on
// one CU; blk<256 -> heads {0,1}, blk>=256 -> heads {3,2} (heavy+light mix).
// Inner loop: fp16 K via v_dot2_f32_f16 (4 inst / 8-dot), zero-slot LDS
// masking (invalid lanes read k=0 -> zero contribution), fp32 V accumulate.
// ---------------------------------------------------------------------------
__global__ __launch_bounds__(448, 4) void attn_kernel(
    const half8* __restrict__ Qh, const half8* __restrict__ Kh,
    const float* __restrict__ V,
    half8* __restrict__ Tpart, float2* __restrict__ LMpart)
{
    int blk = blockIdx.x;
    int p   = blk >> 8;              // pairing half
    int i   = blk & 255;
    int b   = i >> 5;
    int ha  = (i >> 4) & 1;
    int s   = (i >> 1) & 7;
    int th  = i & 1;

    int head = p ? (3 - ha) : ha;
    int dil  = 2*head + 1;           // {1,3,5,7}
    int bh   = b*NHc + head;
    int t0   = th*4;

    int tid = threadIdx.x;           // h*W + w
    int w = tid % Wc;
    int h = tid / Wc;

    __shared__ half8  sK [HWc+1];                       // 7184 B (+ zero slot)
    __shared__ float4 sV0[HWc+1], sV1[HWc+1];           // 14368 B

    sK[tid] = Kh[((size_t)bh*Tc + s)*HWc + tid];
    const float* vp = V + ((size_t)bh*Tc + s)*HWc*DKc;
    sV0[tid] = *(const float4*)(vp + tid*DKc);
    sV1[tid] = *(const float4*)(vp + tid*DKc + 4);
    if (tid == 0) {
        half8 z = {};
        sK[HWc]  = z;
        sV0[HWc] = make_float4(0.f,0.f,0.f,0.f);
        sV1[HWc] = make_float4(0.f,0.f,0.f,0.f);
    }

    H8 q[4];
#pragma unroll
    for (int j = 0; j < 4; ++j)
        q[j].v = Qh[((size_t)bh*Tc + (t0+j))*HWc + tid];

    float4 a0[4], a1[4];
    float l[4], m[4];
#pragma unroll
    for (int j = 0; j < 4; ++j) {
        a0[j] = make_float4(0.f,0.f,0.f,0.f);
        a1[j] = make_float4(0.f,0.f,0.f,0.f);
        l[j] = 0.f; m[j] = -1e30f;
    }

    __syncthreads();

    for (int dy = -3; dy <= 3; ++dy) {
        int hy = h + dy*dil;
        if ((unsigned)hy >= (unsigned)Hc) continue;   // exec-mask row skip
        int rowbase = hy*Wc;
#pragma unroll
        for (int dx = -3; dx <= 3; ++dx) {
            int wx = w + dx*dil;
            bool cv = (unsigned)wx < (unsigned)Wc;
            int idx = cv ? (rowbase + wx) : HWc;      // zero slot if invalid
            float bias = cv ? 0.f : -1e30f;
            H8 k; k.v = sK[idx];
            float4 v0 = sV0[idx], v1 = sV1[idx];
#pragma unroll
            for (int j = 0; j < 4; ++j) {
                float sc = __builtin_amdgcn_fdot2(q[j].h2[0], k.h2[0],
                           __builtin_amdgcn_fdot2(q[j].h2[1], k.h2[1],
                           __builtin_amdgcn_fdot2(q[j].h2[2], k.h2[2],
                           __builtin_amdgcn_fdot2(q[j].h2[3], k.h2[3],
                                                  0.f, false), false), false), false);
                float msc = sc + bias;
                m[j] = fmaxf(m[j], msc);
                l[j] += __expf(msc);
                // invalid lanes: k=0 -> sc=0 -> zero contribution
                a0[j].x = fmaf(sc, v0.x, a0[j].x);
                a0[j].y = fmaf(sc, v0.y, a0[j].y);
                a0[j].z = fmaf(sc, v0.z, a0[j].z);
                a0[j].w = fmaf(sc, v0.w, a0[j].w);
                a1[j].x = fmaf(sc, v1.x, a1[j].x);
                a1[j].y = fmaf(sc, v1.y, a1[j].y);
                a1[j].z = fmaf(sc, v1.z, a1[j].z);
                a1[j].w = fmaf(sc, v1.w, a1[j].w);
            }
        }
    }

    half8*  tp  = Tpart  + (size_t)(bh*Tc + s)*Tc*HWc + tid;
    float2* lmp = LMpart + (size_t)(bh*Tc + s)*Tc*HWc + tid;
#pragma unroll
    for (int j = 0; j < 4; ++j) {
        half8 hv;
        hv[0] = (_Float16)a0[j].x; hv[1] = (_Float16)a0[j].y;
        hv[2] = (_Float16)a0[j].z; hv[3] = (_Float16)a0[j].w;
        hv[4] = (_Float16)a1[j].x; hv[5] = (_Float16)a1[j].y;
        hv[6] = (_Float16)a1[j].z; hv[7] = (_Float16)a1[j].w;
        tp [(t0+j)*HWc] = hv;
        lmp[(t0+j)*HWc] = make_float2(l[j], m[j]);
    }
}

// ---------------------------------------------------------------------------
// Kernel 3: fused combine + output projection.
// grid = 256 blocks (blk = og*64 + bt; the 4 og blocks sharing one bt are 64
// apart -> same XCD, so the 4x replicated Tpart/LM reads are L2-served).
// ---------------------------------------------------------------------------
__global__ __launch_bounds__(448) void outproj_kernel(
    const half8* __restrict__ Tpart, const float2* __restrict__ LMpart,
    const float* __restrict__ Wo, float* __restrict__ out)
{
    int blk = blockIdx.x;            // og*64 + bt
    int og  = blk >> 6;
    int bt  = blk & 63;
    int b   = bt >> 3, t = bt & 7;
    int tid = threadIdx.x;           // h*W + w

    float mv[Cc];
    float MS = 0.f;
#pragma unroll
    for (int head = 0; head < NHc; ++head) {
        int bh = b*NHc + head;
        float acc[DKc];
#pragma unroll
        for (int j = 0; j < DKc; ++j) acc[j] = 0.f;
        float lsum = 0.f, mmax = -1e30f;
#pragma unroll
        for (int s = 0; s < Tc; ++s) {
            half8 u = Tpart[(size_t)((bh*Tc + s)*Tc + t)*HWc + tid];
#pragma unroll
            for (int j = 0; j < DKc; ++j) acc[j] += (float)u[j];
            float2 lm = LMpart[(size_t)((bh*Tc + s)*Tc + t)*HWc + tid];
            lsum += lm.x; mmax = fmaxf(mmax, lm.y);
        }
#pragma unroll
        for (int j = 0; j < DKc; ++j) mv[head*DKc + j] = acc[j];
        MS = fmaxf(MS, __expf(mmax) / lsum);
    }
#pragma unroll
    for (int i = 0; i < 8; ++i) {
        int o = og*8 + i;
        float a = 0.f;
#pragma unroll
        for (int c = 0; c < Cc; ++c) a = fmaf(Wo[o*Cc+c], mv[c], a);
        out[((size_t)bt*Cc + o)*HWc + tid] = a * MS;
    }
}

// ---------------------------------------------------------------------------
extern "C" void kernel_launch(void* const* d_in, const int* in_sizes, int n_in,
                              void* d_out, int out_size, void* d_ws, size_t ws_size,
                              hipStream_t stream) {
    const float* first = (const float*)d_in[0];
    const float* x     = (const float*)d_in[1];
    const float* Wq    = (const float*)d_in[2];
    const float* Wk    = (const float*)d_in[3];
    const float* Wv    = (const float*)d_in[4];
    const float* Wo    = (const float*)d_in[5];
    const float* g     = (const float*)d_in[6];
    const float* bta   = (const float*)d_in[7];
    float* out = (float*)d_out;

    float* ws = (float*)d_ws;
    const size_t N5 = (size_t)Bc*NHc*Tc*HWc*DKc;    // 917504 elements
    half8*  Qh  = (half8*)ws;                        // N5 halves = N5/2 floats
    half8*  Kh  = (half8*)(ws + N5/2);               // N5 halves = N5/2 floats
    float*  V   = ws + N5;                           // N5 floats
    half8*  Tp  = (half8*)(ws + 2*N5);               // 917504 half8 = 4*N5 floats
    float2* LMp = (float2*)(ws + 6*N5);              // 917504 float2 = 2*N5 floats
    // total: 8*N5 floats ~= 29.4 MB  (R9 bug: LMp was at 4*N5, inside Tpart)

    qkv_ln_kernel <<<Bc*Tc*NHc, 448, 0, stream>>>(first, x, Wq, Wk, Wv, g, bta, Qh, Kh, V);
    attn_kernel   <<<512,       448, 0, stream>>>(Qh, Kh, V, Tp, LMp);
    outproj_kernel<<<256,       448, 0, stream>>>(Tp, LMp, Wo, out);
}